// Round 1
// baseline (555.839 us; speedup 1.0000x reference)
//
#include <hip/hip_runtime.h>

// TopK MoE classifier: B=8192 tokens, D=4096, E=16 experts, O=512, top-2.
// Pipeline:
//  k0: transpose+cvt W_e [E][D][O] f32 -> W_bt [E][O][D] bf16 (ws, 64 MiB)
//  k1: router fp32: logits, softmax, top2, weights; per-expert token lists
//      via atomics; prob sums for balance loss
//  k2: grouped GEMM per expert (bf16 MFMA 16x16x32, 128x128 tile, BK=32,
//      double-buffered swizzled LDS); epilogue scatters w*(x@W_e + b_e)
//      into d_out rows with atomicAdd (exactly 2 adds/elem, commutative ->
//      deterministic)
//  k3: finalize balance loss scalar -> d_out[B*O]
// ws layout: [0,64Mi): W_bt | tok lists int[16][8192] | wgt lists f32[16][8192]
//            | cnt int[16] | pisum f32[16]   (needs ~65 MiB of ws)

#define B_ 8192
#define D_ 4096
#define E_ 16
#define O_ 512

typedef unsigned int uint32;
typedef unsigned short ushort_t;
typedef __bf16 bf16_t;
typedef bf16_t bf16x8 __attribute__((ext_vector_type(8)));
typedef float f32x4 __attribute__((ext_vector_type(4)));

__device__ __forceinline__ uint32 bf16_rne(float x) {
  uint32 u = __float_as_uint(x);
  return (u + 0x7fffu + ((u >> 16) & 1u)) >> 16;
}
__device__ __forceinline__ uint4 packbf8(float4 a, float4 b) {
  uint4 r;
  r.x = bf16_rne(a.x) | (bf16_rne(a.y) << 16);
  r.y = bf16_rne(a.z) | (bf16_rne(a.w) << 16);
  r.z = bf16_rne(b.x) | (bf16_rne(b.y) << 16);
  r.w = bf16_rne(b.z) | (bf16_rne(b.w) << 16);
  return r;
}

// ---------------- kernel 0: W_e transpose + f32->bf16 ----------------
__global__ __launch_bounds__(256) void we_transpose(
    const float* __restrict__ We, ushort_t* __restrict__ Wbt) {
  const int e  = blockIdx.z;
  const int d0 = blockIdx.y * 64;
  const int o0 = blockIdx.x * 64;
  __shared__ float t[64][65];
  const int tx = threadIdx.x & 15, ty = threadIdx.x >> 4;

  const float* src = We + ((size_t)e * D_ + d0) * O_ + o0;
#pragma unroll
  for (int p = 0; p < 4; ++p) {
    int dl = ty + p * 16;
    float4 v = *(const float4*)(src + (size_t)dl * O_ + tx * 4);
    t[dl][tx * 4 + 0] = v.x; t[dl][tx * 4 + 1] = v.y;
    t[dl][tx * 4 + 2] = v.z; t[dl][tx * 4 + 3] = v.w;
  }
  __syncthreads();
  ushort_t* dst = Wbt + ((size_t)e * O_ + o0) * D_ + d0;
#pragma unroll
  for (int p = 0; p < 4; ++p) {
    int ol = ty + p * 16;
    uint2 pk;
    pk.x = bf16_rne(t[tx * 4 + 0][ol]) | (bf16_rne(t[tx * 4 + 1][ol]) << 16);
    pk.y = bf16_rne(t[tx * 4 + 2][ol]) | (bf16_rne(t[tx * 4 + 3][ol]) << 16);
    *(uint2*)(dst + (size_t)ol * D_ + tx * 4) = pk;
  }
}

// ---------------- kernel 1: router (fp32) ----------------
// block = 256 thr = 4 waves; each wave owns 4 tokens; block = 16 tokens.
__global__ __launch_bounds__(256) void router(
    const float* __restrict__ feat, const float* __restrict__ Wr,
    const float* __restrict__ br, int* __restrict__ tokL,
    float* __restrict__ wgtL, int* __restrict__ cntA,
    float* __restrict__ pisum) {
  __shared__ float wr[512 * 20];  // chunk of W_r, padded stride 20 (16B aligned)
  __shared__ float pacc[16];
  const int tid = threadIdx.x;
  const int lane = tid & 63, w = tid >> 6;
  if (tid < 16) pacc[tid] = 0.f;

  const int tbase = blockIdx.x * 16 + w * 4;
  float acc[4][16];
#pragma unroll
  for (int i = 0; i < 4; ++i)
#pragma unroll
    for (int e = 0; e < 16; ++e) acc[i][e] = 0.f;

  for (int c = 0; c < 8; ++c) {
    const int cb = c * 512;
    __syncthreads();
#pragma unroll
    for (int q = 0; q < 2; ++q) {
      int r = tid * 2 + q;
      const float4* s = (const float4*)&Wr[(size_t)(cb + r) * 16];
      float4 v0 = s[0], v1 = s[1], v2 = s[2], v3 = s[3];
      float* dp = &wr[r * 20];
      ((float4*)dp)[0] = v0; *(float4*)(dp + 4) = v1;
      *(float4*)(dp + 8) = v2; *(float4*)(dp + 12) = v3;
    }
    __syncthreads();
    for (int it = 0; it < 8; ++it) {
      const int rl = it * 64 + lane;
      const float* wp = &wr[rl * 20];
      float4 w0 = *(const float4*)(wp);
      float4 w1 = *(const float4*)(wp + 4);
      float4 w2 = *(const float4*)(wp + 8);
      float4 w3 = *(const float4*)(wp + 12);
      const int d = cb + rl;
#pragma unroll
      for (int i = 0; i < 4; ++i) {
        float f = feat[(size_t)(tbase + i) * D_ + d];
        acc[i][0]  = fmaf(f, w0.x, acc[i][0]);
        acc[i][1]  = fmaf(f, w0.y, acc[i][1]);
        acc[i][2]  = fmaf(f, w0.z, acc[i][2]);
        acc[i][3]  = fmaf(f, w0.w, acc[i][3]);
        acc[i][4]  = fmaf(f, w1.x, acc[i][4]);
        acc[i][5]  = fmaf(f, w1.y, acc[i][5]);
        acc[i][6]  = fmaf(f, w1.z, acc[i][6]);
        acc[i][7]  = fmaf(f, w1.w, acc[i][7]);
        acc[i][8]  = fmaf(f, w2.x, acc[i][8]);
        acc[i][9]  = fmaf(f, w2.y, acc[i][9]);
        acc[i][10] = fmaf(f, w2.z, acc[i][10]);
        acc[i][11] = fmaf(f, w2.w, acc[i][11]);
        acc[i][12] = fmaf(f, w3.x, acc[i][12]);
        acc[i][13] = fmaf(f, w3.y, acc[i][13]);
        acc[i][14] = fmaf(f, w3.z, acc[i][14]);
        acc[i][15] = fmaf(f, w3.w, acc[i][15]);
      }
    }
  }

#pragma unroll
  for (int i = 0; i < 4; ++i) {
    float l[16];
#pragma unroll
    for (int e = 0; e < 16; ++e) {
      float v = acc[i][e];
#pragma unroll
      for (int m = 32; m >= 1; m >>= 1) v += __shfl_xor(v, m, 64);
      l[e] = v + br[e];
    }
    float mx = l[0];
#pragma unroll
    for (int e = 1; e < 16; ++e) mx = fmaxf(mx, l[e]);
    float p[16];
    float s = 0.f;
#pragma unroll
    for (int e = 0; e < 16; ++e) { p[e] = expf(l[e] - mx); s += p[e]; }
    float inv = 1.f / s;
#pragma unroll
    for (int e = 0; e < 16; ++e) p[e] *= inv;
    // top-2 on probs, first-occurrence tie rule (matches lax.top_k)
    int i0 = 0; float v0 = p[0];
#pragma unroll
    for (int e = 1; e < 16; ++e) if (p[e] > v0) { v0 = p[e]; i0 = e; }
    int i1 = (i0 == 0) ? 1 : 0; float v1 = p[i1];
#pragma unroll
    for (int e = 0; e < 16; ++e)
      if (e != i0 && p[e] > v1) { v1 = p[e]; i1 = e; }
    float denom = fmaxf(v0 + v1, 1e-9f);
    float w0_ = v0 / denom, w1_ = v1 / denom;
    if (lane == 0) {
      int t = tbase + i;
      int s0 = atomicAdd(&cntA[i0], 1);
      tokL[i0 * B_ + s0] = t; wgtL[i0 * B_ + s0] = w0_;
      int s1 = atomicAdd(&cntA[i1], 1);
      tokL[i1 * B_ + s1] = t; wgtL[i1 * B_ + s1] = w1_;
#pragma unroll
      for (int e = 0; e < 16; ++e) atomicAdd(&pacc[e], p[e]);
    }
  }
  __syncthreads();
  if (tid < 16) atomicAdd(&pisum[tid], pacc[tid]);
}

// ---------------- kernel 2: grouped expert GEMM ----------------
// grid (O_/128, B_/128, E); early-exit on row tile >= cnt[e].
#define SOFF(row, kg) ((row) * 32 + ((((kg) ^ ((row) & 3))) << 3))

__global__ __launch_bounds__(256) void moe_gemm(
    const float* __restrict__ feat, const ushort_t* __restrict__ Wbt,
    const float* __restrict__ be, const int* __restrict__ tokL,
    const float* __restrict__ wgtL, const int* __restrict__ cntA,
    float* __restrict__ out) {
  const int e = blockIdx.z;
  const int cnt = cntA[e];
  const int row0 = blockIdx.y * 128;
  if (row0 >= cnt) return;
  const int o0 = blockIdx.x * 128;
  const int tid = threadIdx.x;
  const int lane = tid & 63, wid = tid >> 6;
  const int wm = wid >> 1, wn = wid & 1;

  __shared__ __align__(16) ushort_t As[2][128 * 32];
  __shared__ __align__(16) ushort_t Bs[2][128 * 32];

  // staging: thread covers row (tid>>1), k-groups {skg0, skg0+1}
  const int srow = tid >> 1;
  const int skg0 = (tid & 1) * 2;
  const int tokrow = row0 + srow;
  const int tokid = (tokrow < cnt) ? tokL[e * B_ + tokrow] : 0;
  const float* arow = feat + (size_t)tokid * D_;
  const ushort_t* brow = Wbt + ((size_t)(e * O_ + o0 + srow)) * D_;

  f32x4 acc[4][4] = {};

  // prologue: stage tile 0 into buf 0
#pragma unroll
  for (int q = 0; q < 2; ++q) {
    int kg = skg0 + q;
    float4 a0 = *(const float4*)(arow + kg * 8);
    float4 a1 = *(const float4*)(arow + kg * 8 + 4);
    *(uint4*)&As[0][SOFF(srow, kg)] = packbf8(a0, a1);
    *(uint4*)&Bs[0][SOFF(srow, kg)] = *(const uint4*)(brow + kg * 8);
  }
  __syncthreads();

  const int NT = D_ / 32;  // 128 K-steps
  for (int t = 0; t < NT; ++t) {
    const int cur = t & 1;
    const bool more = (t + 1) < NT;
    float4 pa0[2], pa1[2];
    uint4 pb[2];
    if (more) {
#pragma unroll
      for (int q = 0; q < 2; ++q) {
        int kg = skg0 + q;
        const float* ap = arow + (t + 1) * 32 + kg * 8;
        pa0[q] = *(const float4*)ap;
        pa1[q] = *(const float4*)(ap + 4);
        pb[q] = *(const uint4*)(brow + (t + 1) * 32 + kg * 8);
      }
    }
    bf16x8 af[4], bf[4];
#pragma unroll
    for (int m = 0; m < 4; ++m) {
      int row = wm * 64 + m * 16 + (lane & 15);
      af[m] = *(const bf16x8*)&As[cur][SOFF(row, lane >> 4)];
    }
#pragma unroll
    for (int n = 0; n < 4; ++n) {
      int row = wn * 64 + n * 16 + (lane & 15);
      bf[n] = *(const bf16x8*)&Bs[cur][SOFF(row, lane >> 4)];
    }
#pragma unroll
    for (int m = 0; m < 4; ++m)
#pragma unroll
      for (int n = 0; n < 4; ++n)
        acc[m][n] =
            __builtin_amdgcn_mfma_f32_16x16x32_bf16(af[m], bf[n], acc[m][n], 0, 0, 0);
    if (more) {
      const int nb = cur ^ 1;
#pragma unroll
      for (int q = 0; q < 2; ++q) {
        int kg = skg0 + q;
        *(uint4*)&As[nb][SOFF(srow, kg)] = packbf8(pa0[q], pa1[q]);
        *(uint4*)&Bs[nb][SOFF(srow, kg)] = pb[q];
      }
    }
    __syncthreads();
  }

  // epilogue: out[tok] += w * (acc + b_e[e][o]); exactly 2 adds per element
#pragma unroll
  for (int m = 0; m < 4; ++m) {
#pragma unroll
    for (int i = 0; i < 4; ++i) {
      int lr = wm * 64 + m * 16 + (lane >> 4) * 4 + i;
      int gr = row0 + lr;
      if (gr < cnt) {
        int tk = tokL[e * B_ + gr];
        float wt = wgtL[e * B_ + gr];
#pragma unroll
        for (int n = 0; n < 4; ++n) {
          int o = o0 + wn * 64 + n * 16 + (lane & 15);
          float v = acc[m][n][i] + be[e * O_ + o];
          atomicAdd(&out[(size_t)tk * O_ + o], wt * v);
        }
      }
    }
  }
}

// ---------------- kernel 3: balance loss ----------------
__global__ void finalize(const float* __restrict__ pisum,
                         float* __restrict__ out) {
  if (threadIdx.x == 0) {
    float loss = 0.f;
#pragma unroll
    for (int e = 0; e < 16; ++e) {
      float pi = pisum[e] * (1.f / (float)B_);
      loss += pi * logf(fmaxf(pi, 1e-9f));
    }
    out[(size_t)B_ * O_] = 0.01f * (loss + logf(16.f));
  }
}

extern "C" void kernel_launch(void* const* d_in, const int* in_sizes, int n_in,
                              void* d_out, int out_size, void* d_ws,
                              size_t ws_size, hipStream_t stream) {
  const float* feat = (const float*)d_in[0];
  const float* Wr = (const float*)d_in[1];
  const float* br = (const float*)d_in[2];
  const float* We = (const float*)d_in[3];
  const float* be = (const float*)d_in[4];
  float* out = (float*)d_out;

  char* ws = (char*)d_ws;
  const size_t OFF_TOK = 67108864;            // 64 MiB W_bt
  const size_t OFF_WGT = OFF_TOK + 524288;    // tok lists
  const size_t OFF_CNT = OFF_WGT + 524288;    // wgt lists
  const size_t OFF_PI  = OFF_CNT + 64;
  ushort_t* Wbt = (ushort_t*)ws;
  int* tokL = (int*)(ws + OFF_TOK);
  float* wgtL = (float*)(ws + OFF_WGT);
  int* cntA = (int*)(ws + OFF_CNT);
  float* pisum = (float*)(ws + OFF_PI);

  hipMemsetAsync(out, 0, (size_t)(B_ * O_ + 1) * sizeof(float), stream);
  hipMemsetAsync(ws + OFF_CNT, 0, 128, stream);

  we_transpose<<<dim3(O_ / 64, D_ / 64, E_), 256, 0, stream>>>(We, Wbt);
  router<<<B_ / 16, 256, 0, stream>>>(feat, Wr, br, tokL, wgtL, cntA, pisum);
  moe_gemm<<<dim3(O_ / 128, B_ / 128, E_), 256, 0, stream>>>(
      feat, Wbt, be, tokL, wgtL, cntA, out);
  finalize<<<1, 64, 0, stream>>>(pisum, out);
}

// Round 2
// 505.605 us; speedup vs baseline: 1.0994x; 1.0994x over previous
//
#include <hip/hip_runtime.h>

// TopK MoE classifier: B=8192, D=4096, E=16, O=512, top-2.
//  k0: we_transpose  W_e [E][D][O] f32 -> Wbt [E][O][D] bf16
//  k1: router fp32 (exact top-2 parity) + fused feat f32->bf16 cvt (featbf)
//  k2: moe_gemm grouped bf16 MFMA, 128x128 tile, BK=64, dbuf LDS,
//      global_load_lds staging w/ source-side XOR swizzle (slot^row&7),
//      1 barrier per K-step, issue-early prefetch; atomicAdd epilogue
//      (exactly 2 commutative adds/elem -> deterministic)
//  k3: finalize balance loss
// ws: [0,64Mi) Wbt | [64Mi,128Mi) featbf | tokL | wgtL | cnt | pisum (~129MiB)

#define B_ 8192
#define D_ 4096
#define E_ 16
#define O_ 512
#define BK 64

typedef unsigned int uint32;
typedef unsigned short ushort_t;
typedef __bf16 bf16_t;
typedef bf16_t bf16x8 __attribute__((ext_vector_type(8)));
typedef float f32x4 __attribute__((ext_vector_type(4)));

__device__ __forceinline__ uint32 bf16_rne(float x) {
  uint32 u = __float_as_uint(x);
  return (u + 0x7fffu + ((u >> 16) & 1u)) >> 16;
}

__device__ __forceinline__ void gload16(const void* g, void* l) {
  __builtin_amdgcn_global_load_lds(
      (const __attribute__((address_space(1))) void*)g,
      (__attribute__((address_space(3))) void*)l, 16, 0, 0);
}

// ---------------- kernel 0: W_e transpose + f32->bf16 ----------------
__global__ __launch_bounds__(256) void we_transpose(
    const float* __restrict__ We, ushort_t* __restrict__ Wbt) {
  const int e  = blockIdx.z;
  const int d0 = blockIdx.y * 64;
  const int o0 = blockIdx.x * 64;
  __shared__ float t[64][65];
  const int tx = threadIdx.x & 15, ty = threadIdx.x >> 4;

  const float* src = We + ((size_t)e * D_ + d0) * O_ + o0;
#pragma unroll
  for (int p = 0; p < 4; ++p) {
    int dl = ty + p * 16;
    float4 v = *(const float4*)(src + (size_t)dl * O_ + tx * 4);
    t[dl][tx * 4 + 0] = v.x; t[dl][tx * 4 + 1] = v.y;
    t[dl][tx * 4 + 2] = v.z; t[dl][tx * 4 + 3] = v.w;
  }
  __syncthreads();
  ushort_t* dst = Wbt + ((size_t)e * O_ + o0) * D_ + d0;
#pragma unroll
  for (int p = 0; p < 4; ++p) {
    int ol = ty + p * 16;
    uint2 pk;
    pk.x = bf16_rne(t[tx * 4 + 0][ol]) | (bf16_rne(t[tx * 4 + 1][ol]) << 16);
    pk.y = bf16_rne(t[tx * 4 + 2][ol]) | (bf16_rne(t[tx * 4 + 3][ol]) << 16);
    *(uint2*)(dst + (size_t)ol * D_ + tx * 4) = pk;
  }
}

// ---------------- kernel 1: router (fp32) + feat cvt ----------------
// 256 thr = 4 waves; wave owns 4 tokens; block = 16 tokens. Wr chunked in
// LDS at stride 17 floats (coprime to 32 banks -> 2-way max on reads).
__global__ __launch_bounds__(256) void router(
    const float* __restrict__ feat, const float* __restrict__ Wr,
    const float* __restrict__ br, ushort_t* __restrict__ featbf,
    int* __restrict__ tokL, float* __restrict__ wgtL, int* __restrict__ cntA,
    float* __restrict__ pisum) {
  __shared__ float wrS[512 * 17];
  __shared__ float pacc[16];
  const int tid = threadIdx.x;
  const int lane = tid & 63, w = tid >> 6;
  if (tid < 16) pacc[tid] = 0.f;

  const int tbase = blockIdx.x * 16 + w * 4;
  float acc[4][16];
#pragma unroll
  for (int i = 0; i < 4; ++i)
#pragma unroll
    for (int e = 0; e < 16; ++e) acc[i][e] = 0.f;

  for (int c = 0; c < 8; ++c) {
    const int cb = c * 512;
    __syncthreads();
#pragma unroll
    for (int q = 0; q < 2; ++q) {
      int r = tid * 2 + q;
      const float* s = &Wr[(size_t)(cb + r) * 16];
      float4 v0 = ((const float4*)s)[0], v1 = ((const float4*)s)[1];
      float4 v2 = ((const float4*)s)[2], v3 = ((const float4*)s)[3];
      float* dp = &wrS[r * 17];
      dp[0] = v0.x;  dp[1] = v0.y;  dp[2] = v0.z;  dp[3] = v0.w;
      dp[4] = v1.x;  dp[5] = v1.y;  dp[6] = v1.z;  dp[7] = v1.w;
      dp[8] = v2.x;  dp[9] = v2.y;  dp[10] = v2.z; dp[11] = v2.w;
      dp[12] = v3.x; dp[13] = v3.y; dp[14] = v3.z; dp[15] = v3.w;
    }
    __syncthreads();
#pragma unroll
    for (int si = 0; si < 4; ++si) {
      const int dl = si * 128 + (lane << 1);
      const int d = cb + dl;
      const float* w0p = &wrS[dl * 17];
      const float* w1p = &wrS[(dl + 1) * 17];
      float2 f[4];
#pragma unroll
      for (int i = 0; i < 4; ++i)
        f[i] = *(const float2*)&feat[(size_t)(tbase + i) * D_ + d];
#pragma unroll
      for (int i = 0; i < 4; ++i) {
        uint32 pk = bf16_rne(f[i].x) | (bf16_rne(f[i].y) << 16);
        *(uint32*)&featbf[(size_t)(tbase + i) * D_ + d] = pk;
      }
#pragma unroll
      for (int e = 0; e < 16; ++e) {
        float wa = w0p[e], wb = w1p[e];
#pragma unroll
        for (int i = 0; i < 4; ++i)
          acc[i][e] = fmaf(f[i].x, wa, fmaf(f[i].y, wb, acc[i][e]));
      }
    }
  }

#pragma unroll
  for (int i = 0; i < 4; ++i) {
    float l[16];
#pragma unroll
    for (int e = 0; e < 16; ++e) {
      float v = acc[i][e];
#pragma unroll
      for (int m = 32; m >= 1; m >>= 1) v += __shfl_xor(v, m, 64);
      l[e] = v + br[e];
    }
    float mx = l[0];
#pragma unroll
    for (int e = 1; e < 16; ++e) mx = fmaxf(mx, l[e]);
    float p[16];
    float s = 0.f;
#pragma unroll
    for (int e = 0; e < 16; ++e) { p[e] = expf(l[e] - mx); s += p[e]; }
    float inv = 1.f / s;
#pragma unroll
    for (int e = 0; e < 16; ++e) p[e] *= inv;
    int i0 = 0; float v0 = p[0];
#pragma unroll
    for (int e = 1; e < 16; ++e) if (p[e] > v0) { v0 = p[e]; i0 = e; }
    int i1 = (i0 == 0) ? 1 : 0; float v1 = p[i1];
#pragma unroll
    for (int e = 0; e < 16; ++e)
      if (e != i0 && p[e] > v1) { v1 = p[e]; i1 = e; }
    float denom = fmaxf(v0 + v1, 1e-9f);
    float w0_ = v0 / denom, w1_ = v1 / denom;
    if (lane == 0) {
      int t = tbase + i;
      int s0 = atomicAdd(&cntA[i0], 1);
      tokL[i0 * B_ + s0] = t; wgtL[i0 * B_ + s0] = w0_;
      int s1 = atomicAdd(&cntA[i1], 1);
      tokL[i1 * B_ + s1] = t; wgtL[i1 * B_ + s1] = w1_;
#pragma unroll
      for (int e = 0; e < 16; ++e) atomicAdd(&pacc[e], p[e]);
    }
  }
  __syncthreads();
  if (tid < 16) atomicAdd(&pisum[tid], pacc[tid]);
}

// ---------------- kernel 2: grouped expert GEMM ----------------
// 128x128 tile, BK=64, 4 waves (2x2), dbuf LDS 64 KiB, gload_lds staging.
// LDS row = 64 bf16 = 128 B = 8 slots of 16 B; slot s holds k-group
// kg = s ^ (row&7)  (both-sides swizzle: source pre-swizzled, read swizzled).
__global__ __launch_bounds__(256, 2) void moe_gemm(
    const ushort_t* __restrict__ featbf, const ushort_t* __restrict__ Wbt,
    const float* __restrict__ be, const int* __restrict__ tokL,
    const float* __restrict__ wgtL, const int* __restrict__ cntA,
    float* __restrict__ out) {
  const int e = blockIdx.z;
  const int cnt = cntA[e];
  const int row0 = blockIdx.y * 128;
  if (row0 >= cnt) return;
  const int o0 = blockIdx.x * 128;
  const int tid = threadIdx.x;
  const int lane = tid & 63, w = tid >> 6;
  const int wm = w >> 1, wn = w & 1;

  __shared__ __align__(16) ushort_t As[2][128 * BK];
  __shared__ __align__(16) ushort_t Bs[2][128 * BK];

  // staging geometry: wave w, call j covers rows j*32 + w*8 .. +8
  // lane l: row += (l>>3); LDS dest = base + l*16B (linear);
  // source k-group kg = (l&7) ^ (row&7)  (row&7 == rbase&7, j-independent)
  const int rbase = w * 8 + (lane >> 3);
  const int kgc = (lane & 7) ^ (rbase & 7);
  const ushort_t* asrc[4];
  const ushort_t* bsrc[4];
#pragma unroll
  for (int j = 0; j < 4; ++j) {
    int r = j * 32 + rbase;
    int tr = row0 + r;
    int tok = (tr < cnt) ? tokL[e * B_ + tr] : 0;
    asrc[j] = featbf + (size_t)tok * D_ + kgc * 8;
    bsrc[j] = Wbt + ((size_t)e * O_ + o0 + r) * D_ + kgc * 8;
  }

  f32x4 acc[4][4] = {};
  const int lr = lane & 15;  // fragment row within 16
  const int lg = lane >> 4;  // k-quarter
  // read slots for kk=0/1: s = (kk*4+lg) ^ (lane&7); row&7 == lane&7 here
  const int s0 = ((lg) ^ (lane & 7)) * 8;
  const int s1 = ((4 + lg) ^ (lane & 7)) * 8;

#define STAGE_ALL(buf, t)                                            \
  {                                                                  \
    ushort_t* ab = &As[buf][(w * 8) * BK];                           \
    ushort_t* bb = &Bs[buf][(w * 8) * BK];                           \
    _Pragma("unroll") for (int j = 0; j < 4; ++j) {                  \
      gload16(asrc[j] + (size_t)(t) * BK, ab + j * 32 * BK);         \
      gload16(bsrc[j] + (size_t)(t) * BK, bb + j * 32 * BK);         \
    }                                                                \
  }

#define COMPUTE(buf)                                                 \
  {                                                                  \
    _Pragma("unroll") for (int kk = 0; kk < 2; ++kk) {               \
      const int so = kk ? s1 : s0;                                   \
      bf16x8 af[4], bf[4];                                           \
      _Pragma("unroll") for (int m = 0; m < 4; ++m)                  \
          af[m] = *(const bf16x8*)&As[buf][(wm * 64 + m * 16 + lr) * BK + so]; \
      _Pragma("unroll") for (int n = 0; n < 4; ++n)                  \
          bf[n] = *(const bf16x8*)&Bs[buf][(wn * 64 + n * 16 + lr) * BK + so]; \
      _Pragma("unroll") for (int m = 0; m < 4; ++m)                  \
          _Pragma("unroll") for (int n = 0; n < 4; ++n)              \
              acc[m][n] = __builtin_amdgcn_mfma_f32_16x16x32_bf16(   \
                  af[m], bf[n], acc[m][n], 0, 0, 0);                 \
    }                                                                \
  }

  const int NT = D_ / BK;  // 64 K-steps
  STAGE_ALL(0, 0);
  __syncthreads();
  for (int t = 0; t < NT - 1; ++t) {
    const int cur = t & 1;
    STAGE_ALL(cur ^ 1, t + 1);  // issue-early: latency hides under MFMA
    COMPUTE(cur);
    __syncthreads();            // drains vmcnt -> next buffer ready
  }
  COMPUTE((NT - 1) & 1);

  // epilogue: out[tok] += w * (acc + b_e); exactly 2 commutative adds/elem
#pragma unroll
  for (int m = 0; m < 4; ++m) {
#pragma unroll
    for (int i = 0; i < 4; ++i) {
      int gr = row0 + wm * 64 + m * 16 + (lane >> 4) * 4 + i;
      if (gr < cnt) {
        int tk = tokL[e * B_ + gr];
        float wt = wgtL[e * B_ + gr];
#pragma unroll
        for (int n = 0; n < 4; ++n) {
          int o = o0 + wn * 64 + n * 16 + (lane & 15);
          float v = acc[m][n][i] + be[e * O_ + o];
          atomicAdd(&out[(size_t)tk * O_ + o], wt * v);
        }
      }
    }
  }
#undef STAGE_ALL
#undef COMPUTE
}

// ---------------- kernel 3: balance loss ----------------
__global__ void finalize(const float* __restrict__ pisum,
                         float* __restrict__ out) {
  if (threadIdx.x == 0) {
    float loss = 0.f;
#pragma unroll
    for (int e = 0; e < 16; ++e) {
      float pi = pisum[e] * (1.f / (float)B_);
      loss += pi * logf(fmaxf(pi, 1e-9f));
    }
    out[(size_t)B_ * O_] = 0.01f * (loss + logf(16.f));
  }
}

extern "C" void kernel_launch(void* const* d_in, const int* in_sizes, int n_in,
                              void* d_out, int out_size, void* d_ws,
                              size_t ws_size, hipStream_t stream) {
  const float* feat = (const float*)d_in[0];
  const float* Wr = (const float*)d_in[1];
  const float* br = (const float*)d_in[2];
  const float* We = (const float*)d_in[3];
  const float* be = (const float*)d_in[4];
  float* out = (float*)d_out;

  char* ws = (char*)d_ws;
  const size_t OFF_FEAT = 67108864;            // 64 MiB Wbt
  const size_t OFF_TOK  = OFF_FEAT + 67108864; // 64 MiB featbf
  const size_t OFF_WGT  = OFF_TOK + 524288;
  const size_t OFF_CNT  = OFF_WGT + 524288;
  const size_t OFF_PI   = OFF_CNT + 64;
  ushort_t* Wbt = (ushort_t*)ws;
  ushort_t* featbf = (ushort_t*)(ws + OFF_FEAT);
  int* tokL = (int*)(ws + OFF_TOK);
  float* wgtL = (float*)(ws + OFF_WGT);
  int* cntA = (int*)(ws + OFF_CNT);
  float* pisum = (float*)(ws + OFF_PI);

  hipMemsetAsync(out, 0, (size_t)(B_ * O_ + 1) * sizeof(float), stream);
  hipMemsetAsync(ws + OFF_CNT, 0, 128, stream);

  router<<<B_ / 16, 256, 0, stream>>>(feat, Wr, br, featbf, tokL, wgtL, cntA,
                                      pisum);
  we_transpose<<<dim3(O_ / 64, D_ / 64, E_), 256, 0, stream>>>(We, Wbt);
  moe_gemm<<<dim3(O_ / 128, B_ / 128, E_), 256, 0, stream>>>(
      featbf, Wbt, be, tokL, wgtL, cntA, out);
  finalize<<<1, 64, 0, stream>>>(pisum, out);
}